// Round 12
// baseline (222.657 us; speedup 1.0000x reference)
//
#include <hip/hip_runtime.h>
#include <hip/hip_bf16.h>

typedef __attribute__((ext_vector_type(8))) short bf16x8;   // 8 bf16 = 4 VGPRs
typedef __attribute__((ext_vector_type(4))) float f32x4;
typedef unsigned short u16t;

#define DEVINL static __device__ __forceinline__

DEVINL u16t f2bf(float f) {
  union { __hip_bfloat16 h; u16t u; } cv;
  cv.h = __float2bfloat16(f);
  return cv.u;
}

// packed f32x2 -> bf16x2 (dst.lo = cvt(a), dst.hi = cvt(b)); no builtin on gfx950
DEVINL unsigned cvt_pk_bf16(float a, float b) {
  unsigned r;
  asm("v_cvt_pk_bf16_f32 %0, %1, %2" : "=v"(r) : "v"(a), "v"(b));
  return r;
}

DEVINL void async16(void* lds, const void* g) {
  __builtin_amdgcn_global_load_lds((const __attribute__((address_space(1))) void*)g,
                                   (__attribute__((address_space(3))) void*)lds,
                                   16, 0, 0);
}

// ---------------------------------------------------------------------------
// fp32 -> bf16 conversion for x (4M elems) + Wq/Wk/Wv/Wo (1M each).
// Wq/Wk/Wv destinations are CONTIGUOUS -> later treated as one [3072][1024].
// ---------------------------------------------------------------------------
__global__ __launch_bounds__(256) void convert_bf16(
    const float* __restrict__ x,  const float* __restrict__ wq,
    const float* __restrict__ wk, const float* __restrict__ wv,
    const float* __restrict__ wo,
    u16t* __restrict__ xb, u16t* __restrict__ wqb, u16t* __restrict__ wkb,
    u16t* __restrict__ wvb, u16t* __restrict__ wob) {
  const int blk = blockIdx.x;
  const float* src; u16t* dst; size_t off;
  if (blk < 4096)      { src = x;  dst = xb;  off = (size_t)blk * 1024; }
  else if (blk < 5120) { src = wq; dst = wqb; off = (size_t)(blk - 4096) * 1024; }
  else if (blk < 6144) { src = wk; dst = wkb; off = (size_t)(blk - 5120) * 1024; }
  else if (blk < 7168) { src = wv; dst = wvb; off = (size_t)(blk - 6144) * 1024; }
  else                 { src = wo; dst = wob; off = (size_t)(blk - 7168) * 1024; }
  const size_t i = off + (size_t)threadIdx.x * 4;
  const float4 v = *(const float4*)&src[i];
  ushort4 r;
  r.x = f2bf(v.x); r.y = f2bf(v.y); r.z = f2bf(v.z); r.w = f2bf(v.w);
  *(ushort4*)&dst[i] = r;
}

// ---------------------------------------------------------------------------
// C[m,n] = sum_k A[m,k]*B[n,k].  A:[M,K], B:[N,K] row-major bf16.
// Tile BM x 128 (BM = 128 or 64). Cross-panel double-buffered BK=32 panels
// (R10: neutral vs 2-barrier form, kept as equivalent).
// MODE 0: C0 row-major [M,N] fp32.
// MODE 1 (fused QKV, N=3072), nz = n0>>10:
//   nz==0 (Q): head-split bf16, PRE-SCALED by 0.125/ln2 (softmax fold)
//   nz==1 (K): frag-tiled: ((t>>4)*8+(d>>3))*128 + (t&15)*8 + (d&7)
//   nz==2 (V): frag-tiled: ((d>>4)*256+(t>>3))*128 + (d&15)*8 + (t&7)
// ---------------------------------------------------------------------------
template <int MODE, int BM>
__global__ __launch_bounds__(256) void gemm_bt(
    const u16t* __restrict__ A, const u16t* __restrict__ B,
    void* __restrict__ C0, void* __restrict__ C1, void* __restrict__ C2,
    int M, int N, int K) {
  constexpr int MI = BM / 32;        // row-frags of 16 per wave (wave = BM/2 rows)
  __shared__ u16t As[2][BM * 32];    // ping-pong across BK=32 panels
  __shared__ u16t Bs[2][128 * 32];

  const int tid = threadIdx.x;
  const int lane = tid & 63;
  const int w = tid >> 6;
  const int wm = w >> 1, wn = w & 1;
  const int quad = lane >> 4, cl = lane & 15;
  const int m0 = blockIdx.y * BM;
  const int n0 = blockIdx.x * 128;

  const int srow = lane >> 2;        // row within 16-row staging chunk
  const int scol = (lane & 3) * 8;   // 8-elem (16B) column chunk

  f32x4 acc[MI][4] = {};

  #define STAGEP(b, kp)                                                       \
    {                                                                         \
      _Pragma("unroll")                                                       \
      for (int ii = 0; ii < BM / 64; ++ii) {                                  \
        const int c = w + ii * 4;                                             \
        async16(&As[b][c * 512],                                              \
                &A[(size_t)(m0 + c * 16 + srow) * K + (kp) * 32 + scol]);     \
      }                                                                       \
      _Pragma("unroll")                                                       \
      for (int ii = 0; ii < 2; ++ii) {                                        \
        const int c = w + ii * 4;                                             \
        async16(&Bs[b][c * 512],                                              \
                &B[(size_t)(n0 + c * 16 + srow) * K + (kp) * 32 + scol]);     \
      }                                                                       \
    }

  #define COMPUTEP(b)                                                         \
    {                                                                         \
      bf16x8 af[MI], bfr[4];                                                  \
      _Pragma("unroll")                                                       \
      for (int i = 0; i < MI; ++i)                                            \
        af[i] = *(const bf16x8*)&As[b][(wm * (BM / 2) + i * 16 + cl) * 32 + quad * 8]; \
      _Pragma("unroll")                                                       \
      for (int j = 0; j < 4; ++j)                                             \
        bfr[j] = *(const bf16x8*)&Bs[b][(wn * 64 + j * 16 + cl) * 32 + quad * 8]; \
      _Pragma("unroll")                                                       \
      for (int i = 0; i < MI; ++i)                                            \
        _Pragma("unroll")                                                     \
        for (int j = 0; j < 4; ++j)                                           \
          acc[i][j] = __builtin_amdgcn_mfma_f32_16x16x32_bf16(af[i], bfr[j], acc[i][j], 0, 0, 0); \
    }

  const int NP = K >> 5;             // BK=32 panels (K=1024 -> 32, even)
  STAGEP(0, 0);
  __syncthreads();                   // drain panel 0
  for (int kp = 0; kp < NP; kp += 2) {
    if (kp + 1 < NP) STAGEP(1, kp + 1);
    COMPUTEP(0);
    __syncthreads();                 // stage(kp+1) landed; buf0 free
    if (kp + 2 < NP) STAGEP(0, kp + 2);
    COMPUTEP(1);
    __syncthreads();                 // stage(kp+2) landed; buf1 free
  }
  #undef STAGEP
  #undef COMPUTEP

  const int nz = n0 >> 10;           // MODE1: weight id (block-uniform)
  #pragma unroll
  for (int i = 0; i < MI; ++i)
    #pragma unroll
    for (int j = 0; j < 4; ++j) {
      const int mb = m0 + wm * (BM / 2) + i * 16 + quad * 4;  // 4 consecutive m
      const int n  = n0 + wn * 64 + j * 16 + cl;
      if (MODE == 0) {
        #pragma unroll
        for (int r = 0; r < 4; ++r)
          ((float*)C0)[(size_t)(mb + r) * N + n] = acc[i][j][r];
      } else {
        const int nw = n & 1023, h = nw >> 6, d = nw & 63;
        const int b = mb >> 11, tb = mb & 2047;
        const size_t bh = (size_t)(b * 16 + h);
        if (nz == 2) {
          ushort4 v4;
          v4.x = f2bf(acc[i][j][0]); v4.y = f2bf(acc[i][j][1]);
          v4.z = f2bf(acc[i][j][2]); v4.w = f2bf(acc[i][j][3]);
          const size_t addr = (bh << 17) +
              (size_t)(((d >> 4) * 256 + (tb >> 3)) * 128 + (d & 15) * 8 + (tb & 7));
          *(ushort4*)&((u16t*)C2)[addr] = v4;
        } else if (nz == 1) {
          const size_t basea = (bh << 17) +
              (size_t)(((tb >> 4) * 8 + (d >> 3)) * 128 + (d & 7));
          #pragma unroll
          for (int r = 0; r < 4; ++r)
            ((u16t*)C1)[basea + ((tb & 15) + r) * 8] = f2bf(acc[i][j][r]);
        } else {
          // Q: pre-scale by 0.125/ln2 so flash softmax is p = exp2(s)
          #pragma unroll
          for (int r = 0; r < 4; ++r)
            ((u16t*)C0)[(bh * 2048 + tb + r) * 64 + d] =
                f2bf(acc[i][j][r] * 0.18033688011112043f);
        }
      }
    }
}

// ---------------------------------------------------------------------------
// Flash attention V13 = R9 (62.7us) + cross-tile K prefetch (K ONLY, fenced).
// Grid (x=32 bh, y=16 q-chunks), block 256 = 4 independent waves; wave owns
// 32 q-rows (two 16-row halves sharing one K/V fetch); bh-pinned XCDs.
//
// Per-tile schedule (in-order vmcnt gives counted waits, no drains):
//   QK MFMAs on kf_cur (preloaded during prev PV)      [wait kf_cur]
//   issue 16 V loads (fenced)
//   exp2/cvt/P-write (covers V latency)
//   issue 16 K loads for NEXT tile (fenced)            [kf_next in flight]
//   PV MFMAs                                           [wait vf; kf_next flies]
// R6's failure mode avoided: ONLY K is cross-tile double-buffered (kA/kB,
// unroll-by-2, compile-time indices); vf tile-scoped; s0/s1 dead before PV.
// Peak live ~190 VGPR < 256 cap. SPILL TRIPWIRE: WRITE_SIZE must stay 8.19MB.
//  - Swapped QK^T: s = mfma(K,Q) -> lane holds P[q=cl][k=js*16+quad*4+r].
//  - P scratch stride 136 u16; b64 write + b128 read occupancy-minimal.
//  - Row sums via ones-MFMA; rows align with O rows -> lane-local rcp.
// No online max (scores pre-scaled, exp2 arg |.| small, fp32-safe).
// ---------------------------------------------------------------------------
__global__ __launch_bounds__(256, 2) void flash_attn(
    const u16t* __restrict__ Q, const u16t* __restrict__ Kt,
    const u16t* __restrict__ Vt, u16t* __restrict__ Y) {
  __shared__ u16t Ps[4 * 32 * 136];   // per-wave 32-row P scratch (34.8 KB)
  const int tid = threadIdx.x;
  const int lane = tid & 63;
  const int w = tid >> 6;
  const int quad = lane >> 4, cl = lane & 15;
  const int bh = blockIdx.x;          // bh on x: id%8==bh%8 pins bh to one XCD
  const int q0 = blockIdx.y * 128 + w * 32;
  const u16t* Kb = Kt + ((size_t)bh << 17);
  const u16t* Vb = Vt + ((size_t)bh << 17);

  // Q fragments for both halves, tile-invariant (row q0+16h+cl, k=ks*32+quad*8+j)
  bf16x8 aq[2][2];
  #pragma unroll
  for (int h = 0; h < 2; ++h)
    #pragma unroll
    for (int ks = 0; ks < 2; ++ks)
      aq[h][ks] = *(const bf16x8*)&Q[((size_t)bh * 2048 + q0 + 16 * h + cl) * 64 + ks * 32 + quad * 8];

  bf16x8 ones8;                       // bf16 1.0 splat for row-sum MFMA
  #pragma unroll
  for (int i = 0; i < 8; ++i) ones8[i] = (short)0x3F80;

  f32x4 o[2][4] = {};                 // [half][ds]: row=quad*4+r, col=ds*16+cl
  f32x4 psum[2] = {};                 // row sums, same row mapping as o

  u16t* Pw = &Ps[w * 32 * 136];       // half1 at +16*136

  // K frag (ks,js) of tile jt: Kb[(jt*64 + js*8 + ks*4)*128 + lane*8]
  bf16x8 kA[2][8], kB[2][8];
  #pragma unroll
  for (int ks = 0; ks < 2; ++ks)
    #pragma unroll
    for (int js = 0; js < 8; ++js)
      kA[ks][js] = *(const bf16x8*)&Kb[(size_t)((js * 8 + ks * 4) * 128) + lane * 8];
  __builtin_amdgcn_sched_barrier(0);

  #define TILE_STEP(jt, kc, kn)                                               \
  {                                                                           \
    /* QK: 32 MFMAs on kc (preloaded) */                                      \
    f32x4 s0[8] = {}, s1[8] = {};                                             \
    _Pragma("unroll")                                                         \
    for (int ks = 0; ks < 2; ++ks) {                                          \
      _Pragma("unroll")                                                       \
      for (int js = 0; js < 8; ++js)                                          \
        s0[js] = __builtin_amdgcn_mfma_f32_16x16x32_bf16(kc[ks][js], aq[0][ks], s0[js], 0, 0, 0); \
      _Pragma("unroll")                                                       \
      for (int js = 0; js < 8; ++js)                                          \
        s1[js] = __builtin_amdgcn_mfma_f32_16x16x32_bf16(kc[ks][js], aq[1][ks], s1[js], 0, 0, 0); \
    }                                                                         \
    /* issue ALL 16 V loads (fenced): exp2/cvt/P-write covers latency */      \
    bf16x8 vf[4][4];                                                          \
    _Pragma("unroll")                                                         \
    for (int ks = 0; ks < 4; ++ks)                                            \
      _Pragma("unroll")                                                       \
      for (int ds = 0; ds < 4; ++ds)                                          \
        vf[ks][ds] = *(const bf16x8*)&Vb[(size_t)((ds * 256 + (jt) * 16 + ks * 4) * 128) + lane * 8]; \
    __builtin_amdgcn_sched_barrier(0);                                        \
    /* p = exp2(s); pack pairs -> one b64 write per (half, js) */             \
    _Pragma("unroll")                                                         \
    for (int js = 0; js < 8; ++js) {                                          \
      uint2 pk0, pk1;                                                         \
      pk0.x = cvt_pk_bf16(__builtin_exp2f(s0[js][0]), __builtin_exp2f(s0[js][1])); \
      pk0.y = cvt_pk_bf16(__builtin_exp2f(s0[js][2]), __builtin_exp2f(s0[js][3])); \
      *(uint2*)&Pw[cl * 136 + js * 16 + quad * 4] = pk0;                      \
      pk1.x = cvt_pk_bf16(__builtin_exp2f(s1[js][0]), __builtin_exp2f(s1[js][1])); \
      pk1.y = cvt_pk_bf16(__builtin_exp2f(s1[js][2]), __builtin_exp2f(s1[js][3])); \
      *(uint2*)&Pw[(16 + cl) * 136 + js * 16 + quad * 4] = pk1;               \
    }                                                                         \
    __builtin_amdgcn_sched_barrier(0);                                        \
    /* cross-tile K prefetch: flies under PV + vf wait */                     \
    if ((jt) + 1 < 16) {                                                      \
      _Pragma("unroll")                                                       \
      for (int ks = 0; ks < 2; ++ks)                                          \
        _Pragma("unroll")                                                     \
        for (int js = 0; js < 8; ++js)                                        \
          kn[ks][js] = *(const bf16x8*)&Kb[(size_t)((((jt) + 1) * 64 + js * 8 + ks * 4) * 128) + lane * 8]; \
      __builtin_amdgcn_sched_barrier(0);                                      \
    }                                                                         \
    /* O += P @ V ; row sums via ones-MFMA (waits vf only: counted vmcnt) */  \
    _Pragma("unroll")                                                         \
    for (int ks = 0; ks < 4; ++ks) {                                          \
      const bf16x8 ap0 = *(const bf16x8*)&Pw[cl * 136 + ks * 32 + quad * 8];  \
      const bf16x8 ap1 = *(const bf16x8*)&Pw[(16 + cl) * 136 + ks * 32 + quad * 8]; \
      psum[0] = __builtin_amdgcn_mfma_f32_16x16x32_bf16(ap0, ones8, psum[0], 0, 0, 0); \
      psum[1] = __builtin_amdgcn_mfma_f32_16x16x32_bf16(ap1, ones8, psum[1], 0, 0, 0); \
      _Pragma("unroll")                                                       \
      for (int ds = 0; ds < 4; ++ds) {                                        \
        o[0][ds] = __builtin_amdgcn_mfma_f32_16x16x32_bf16(ap0, vf[ks][ds], o[0][ds], 0, 0, 0); \
        o[1][ds] = __builtin_amdgcn_mfma_f32_16x16x32_bf16(ap1, vf[ks][ds], o[1][ds], 0, 0, 0); \
      }                                                                       \
    }                                                                         \
  }

  for (int jt = 0; jt < 16; jt += 2) {
    TILE_STEP(jt, kA, kB);            // compute kA, prefetch -> kB
    TILE_STEP(jt + 1, kB, kA);        // compute kB, prefetch -> kA
  }
  #undef TILE_STEP

  // psum rows align with o rows: lane-local normalize, no shuffles
  const int b = bh >> 4, hd = bh & 15;
  #pragma unroll
  for (int h = 0; h < 2; ++h) {
    float inv[4];
    #pragma unroll
    for (int r = 0; r < 4; ++r) inv[r] = __builtin_amdgcn_rcpf(psum[h][r]);
    #pragma unroll
    for (int ds = 0; ds < 4; ++ds)
      #pragma unroll
      for (int r = 0; r < 4; ++r) {
        const int t = q0 + 16 * h + quad * 4 + r;
        const int d = ds * 16 + cl;
        Y[((size_t)b * 2048 + t) * 1024 + hd * 64 + d] = f2bf(o[h][ds][r] * inv[r]);
      }
  }
}

extern "C" void kernel_launch(void* const* d_in, const int* in_sizes, int n_in,
                              void* d_out, int out_size, void* d_ws, size_t ws_size,
                              hipStream_t stream) {
  (void)in_sizes; (void)n_in; (void)out_size; (void)ws_size;
  const float* x  = (const float*)d_in[0];
  const float* Wq = (const float*)d_in[1];
  const float* Wk = (const float*)d_in[2];
  const float* Wv = (const float*)d_in[3];
  const float* Wo = (const float*)d_in[4];

  char* ws = (char*)d_ws;
  const size_t MB = 1024 * 1024;
  u16t* xb  = (u16t*)(ws);               // [4096][1024] bf16 (8 MB) — aliased by Yw
  u16t* Wqb = (u16t*)(ws + 8 * MB);      // Wq/Wk/Wv contiguous -> [3072][1024]
  u16t* Wkb = (u16t*)(ws + 10 * MB);
  u16t* Wvb = (u16t*)(ws + 12 * MB);
  u16t* Wob = (u16t*)(ws + 14 * MB);
  u16t* Qw  = (u16t*)(ws + 16 * MB);     // [32][2048][64] bf16 head-split (pre-scaled)
  u16t* Ktw = (u16t*)(ws + 24 * MB);     // [32] fragment-tiled K'
  u16t* Vtw = (u16t*)(ws + 32 * MB);     // [32] fragment-tiled V'
  u16t* Yw  = xb;                        // safe alias: xb dead after QKV gemm

  convert_bf16<<<8192, 256, 0, stream>>>(x, Wq, Wk, Wv, Wo, xb, Wqb, Wkb, Wvb, Wob);
  // fused QKV: B = [3072][1024], output target selected by n0>>10
  gemm_bt<1, 128><<<dim3(24, 32), 256, 0, stream>>>(
      xb, Wqb, Qw, Ktw, Vtw, 4096, 3072, 1024);
  flash_attn<<<dim3(32, 16), 256, 0, stream>>>(Qw, Ktw, Vtw, Yw);
  // out-proj: BM=64 -> 512 blocks (2/CU) so barrier drains overlap
  gemm_bt<0, 64><<<dim3(8, 64), 256, 0, stream>>>(
      Yw, Wob, d_out, d_out, d_out, 4096, 1024, 1024);
}

// Round 13
// 196.082 us; speedup vs baseline: 1.1355x; 1.1355x over previous
//
#include <hip/hip_runtime.h>
#include <hip/hip_bf16.h>

typedef __attribute__((ext_vector_type(8))) short bf16x8;   // 8 bf16 = 4 VGPRs
typedef __attribute__((ext_vector_type(4))) float f32x4;
typedef unsigned short u16t;

#define DEVINL static __device__ __forceinline__

DEVINL u16t f2bf(float f) {
  union { __hip_bfloat16 h; u16t u; } cv;
  cv.h = __float2bfloat16(f);
  return cv.u;
}

// packed f32x2 -> bf16x2 (dst.lo = cvt(a), dst.hi = cvt(b)); no builtin on gfx950
DEVINL unsigned cvt_pk_bf16(float a, float b) {
  unsigned r;
  asm("v_cvt_pk_bf16_f32 %0, %1, %2" : "=v"(r) : "v"(a), "v"(b));
  return r;
}

DEVINL void async16(void* lds, const void* g) {
  __builtin_amdgcn_global_load_lds((const __attribute__((address_space(1))) void*)g,
                                   (__attribute__((address_space(3))) void*)lds,
                                   16, 0, 0);
}

// ---------------------------------------------------------------------------
// fp32 -> bf16 conversion for x (4M elems) + Wq/Wk/Wv/Wo (1M each).
// Wq/Wk/Wv destinations are CONTIGUOUS -> later treated as one [3072][1024].
// ---------------------------------------------------------------------------
__global__ __launch_bounds__(256) void convert_bf16(
    const float* __restrict__ x,  const float* __restrict__ wq,
    const float* __restrict__ wk, const float* __restrict__ wv,
    const float* __restrict__ wo,
    u16t* __restrict__ xb, u16t* __restrict__ wqb, u16t* __restrict__ wkb,
    u16t* __restrict__ wvb, u16t* __restrict__ wob) {
  const int blk = blockIdx.x;
  const float* src; u16t* dst; size_t off;
  if (blk < 4096)      { src = x;  dst = xb;  off = (size_t)blk * 1024; }
  else if (blk < 5120) { src = wq; dst = wqb; off = (size_t)(blk - 4096) * 1024; }
  else if (blk < 6144) { src = wk; dst = wkb; off = (size_t)(blk - 5120) * 1024; }
  else if (blk < 7168) { src = wv; dst = wvb; off = (size_t)(blk - 6144) * 1024; }
  else                 { src = wo; dst = wob; off = (size_t)(blk - 7168) * 1024; }
  const size_t i = off + (size_t)threadIdx.x * 4;
  const float4 v = *(const float4*)&src[i];
  ushort4 r;
  r.x = f2bf(v.x); r.y = f2bf(v.y); r.z = f2bf(v.z); r.w = f2bf(v.w);
  *(ushort4*)&dst[i] = r;
}

// ---------------------------------------------------------------------------
// C[m,n] = sum_k A[m,k]*B[n,k].  A:[M,K], B:[N,K] row-major bf16.
// Tile BM x 128 (BM = 128 or 64). Cross-panel double-buffered BK=32 panels
// (R10: neutral vs 2-barrier form, kept as equivalent).
// MODE 0: C0 row-major [M,N] fp32.
// MODE 1 (fused QKV, N=3072), nz = n0>>10:
//   nz==0 (Q): head-split bf16, PRE-SCALED by 0.125/ln2 (softmax fold)
//   nz==1 (K): frag-tiled: ((t>>4)*8+(d>>3))*128 + (t&15)*8 + (d&7)
//   nz==2 (V): frag-tiled: ((d>>4)*256+(t>>3))*128 + (d&15)*8 + (t&7)
// ---------------------------------------------------------------------------
template <int MODE, int BM>
__global__ __launch_bounds__(256) void gemm_bt(
    const u16t* __restrict__ A, const u16t* __restrict__ B,
    void* __restrict__ C0, void* __restrict__ C1, void* __restrict__ C2,
    int M, int N, int K) {
  constexpr int MI = BM / 32;        // row-frags of 16 per wave (wave = BM/2 rows)
  __shared__ u16t As[2][BM * 32];    // ping-pong across BK=32 panels
  __shared__ u16t Bs[2][128 * 32];

  const int tid = threadIdx.x;
  const int lane = tid & 63;
  const int w = tid >> 6;
  const int wm = w >> 1, wn = w & 1;
  const int quad = lane >> 4, cl = lane & 15;
  const int m0 = blockIdx.y * BM;
  const int n0 = blockIdx.x * 128;

  const int srow = lane >> 2;        // row within 16-row staging chunk
  const int scol = (lane & 3) * 8;   // 8-elem (16B) column chunk

  f32x4 acc[MI][4] = {};

  #define STAGEP(b, kp)                                                       \
    {                                                                         \
      _Pragma("unroll")                                                       \
      for (int ii = 0; ii < BM / 64; ++ii) {                                  \
        const int c = w + ii * 4;                                             \
        async16(&As[b][c * 512],                                              \
                &A[(size_t)(m0 + c * 16 + srow) * K + (kp) * 32 + scol]);     \
      }                                                                       \
      _Pragma("unroll")                                                       \
      for (int ii = 0; ii < 2; ++ii) {                                        \
        const int c = w + ii * 4;                                             \
        async16(&Bs[b][c * 512],                                              \
                &B[(size_t)(n0 + c * 16 + srow) * K + (kp) * 32 + scol]);     \
      }                                                                       \
    }

  #define COMPUTEP(b)                                                         \
    {                                                                         \
      bf16x8 af[MI], bfr[4];                                                  \
      _Pragma("unroll")                                                       \
      for (int i = 0; i < MI; ++i)                                            \
        af[i] = *(const bf16x8*)&As[b][(wm * (BM / 2) + i * 16 + cl) * 32 + quad * 8]; \
      _Pragma("unroll")                                                       \
      for (int j = 0; j < 4; ++j)                                             \
        bfr[j] = *(const bf16x8*)&Bs[b][(wn * 64 + j * 16 + cl) * 32 + quad * 8]; \
      _Pragma("unroll")                                                       \
      for (int i = 0; i < MI; ++i)                                            \
        _Pragma("unroll")                                                     \
        for (int j = 0; j < 4; ++j)                                           \
          acc[i][j] = __builtin_amdgcn_mfma_f32_16x16x32_bf16(af[i], bfr[j], acc[i][j], 0, 0, 0); \
    }

  const int NP = K >> 5;             // BK=32 panels (K=1024 -> 32, even)
  STAGEP(0, 0);
  __syncthreads();                   // drain panel 0
  for (int kp = 0; kp < NP; kp += 2) {
    if (kp + 1 < NP) STAGEP(1, kp + 1);
    COMPUTEP(0);
    __syncthreads();                 // stage(kp+1) landed; buf0 free
    if (kp + 2 < NP) STAGEP(0, kp + 2);
    COMPUTEP(1);
    __syncthreads();                 // stage(kp+2) landed; buf1 free
  }
  #undef STAGEP
  #undef COMPUTEP

  const int nz = n0 >> 10;           // MODE1: weight id (block-uniform)
  #pragma unroll
  for (int i = 0; i < MI; ++i)
    #pragma unroll
    for (int j = 0; j < 4; ++j) {
      const int mb = m0 + wm * (BM / 2) + i * 16 + quad * 4;  // 4 consecutive m
      const int n  = n0 + wn * 64 + j * 16 + cl;
      if (MODE == 0) {
        #pragma unroll
        for (int r = 0; r < 4; ++r)
          ((float*)C0)[(size_t)(mb + r) * N + n] = acc[i][j][r];
      } else {
        const int nw = n & 1023, h = nw >> 6, d = nw & 63;
        const int b = mb >> 11, tb = mb & 2047;
        const size_t bh = (size_t)(b * 16 + h);
        if (nz == 2) {
          ushort4 v4;
          v4.x = f2bf(acc[i][j][0]); v4.y = f2bf(acc[i][j][1]);
          v4.z = f2bf(acc[i][j][2]); v4.w = f2bf(acc[i][j][3]);
          const size_t addr = (bh << 17) +
              (size_t)(((d >> 4) * 256 + (tb >> 3)) * 128 + (d & 15) * 8 + (tb & 7));
          *(ushort4*)&((u16t*)C2)[addr] = v4;
        } else if (nz == 1) {
          const size_t basea = (bh << 17) +
              (size_t)(((tb >> 4) * 8 + (d >> 3)) * 128 + (d & 7));
          #pragma unroll
          for (int r = 0; r < 4; ++r)
            ((u16t*)C1)[basea + ((tb & 15) + r) * 8] = f2bf(acc[i][j][r]);
        } else {
          // Q: pre-scale by 0.125/ln2 so flash softmax is p = exp2(s)
          #pragma unroll
          for (int r = 0; r < 4; ++r)
            ((u16t*)C0)[(bh * 2048 + tb + r) * 64 + d] =
                f2bf(acc[i][j][r] * 0.18033688011112043f);
        }
      }
    }
}

// ---------------------------------------------------------------------------
// Flash attention V14 = R9 verbatim (62.7us, VGPR 108, no spill) + T5
// setprio around MFMA clusters.
// R12's cross-tile K prefetch REVERTED: allocator chose 128-reg + 160MB
// scratch spill over a 190-reg schedule (2nd failure of that idea; final).
// Grid (x=32 bh, y=16 q-chunks), block 256 = 4 independent barrier-free
// waves (2/SIMD) -- the m191 regime where setprio measured +4-7% on attn:
// co-resident waves sit in different phases; priority lets the MFMA-entering
// wave win issue arbitration over the exp2/VALU wave.
//  - All 16 K-frag b128 loads hoisted ahead of QK, pinned by sched_barrier(0).
//  - All 16 V-frag b128 loads issue between QK and exp2/P-write (fenced).
//  - Swapped QK^T: s = mfma(K,Q) -> lane holds P[q=cl][k=js*16+quad*4+r].
//  - P scratch stride 136 u16; b64 write + b128 read occupancy-minimal.
//  - Row sums via ones-MFMA; rows align with O rows -> lane-local rcp.
// No online max (scores pre-scaled, exp2 arg |.| small, fp32-safe).
// ---------------------------------------------------------------------------
__global__ __launch_bounds__(256, 2) void flash_attn(
    const u16t* __restrict__ Q, const u16t* __restrict__ Kt,
    const u16t* __restrict__ Vt, u16t* __restrict__ Y) {
  __shared__ u16t Ps[4 * 32 * 136];   // per-wave 32-row P scratch (34.8 KB)
  const int tid = threadIdx.x;
  const int lane = tid & 63;
  const int w = tid >> 6;
  const int quad = lane >> 4, cl = lane & 15;
  const int bh = blockIdx.x;          // bh on x: id%8==bh%8 pins bh to one XCD
  const int q0 = blockIdx.y * 128 + w * 32;
  const u16t* Kb = Kt + ((size_t)bh << 17);
  const u16t* Vb = Vt + ((size_t)bh << 17);

  // Q fragments for both halves, tile-invariant (row q0+16h+cl, k=ks*32+quad*8+j)
  bf16x8 aq[2][2];
  #pragma unroll
  for (int h = 0; h < 2; ++h)
    #pragma unroll
    for (int ks = 0; ks < 2; ++ks)
      aq[h][ks] = *(const bf16x8*)&Q[((size_t)bh * 2048 + q0 + 16 * h + cl) * 64 + ks * 32 + quad * 8];

  bf16x8 ones8;                       // bf16 1.0 splat for row-sum MFMA
  #pragma unroll
  for (int i = 0; i < 8; ++i) ones8[i] = (short)0x3F80;

  f32x4 o[2][4] = {};                 // [half][ds]: row=quad*4+r, col=ds*16+cl
  f32x4 psum[2] = {};                 // row sums, same row mapping as o

  u16t* Pw = &Ps[w * 32 * 136];       // half1 at +16*136

  for (int jt = 0; jt < 16; ++jt) {
    const int j0 = jt * 128;

    // ---- QK: all 16 K loads first (fenced), then 32 MFMAs -> 1 wait-point
    bf16x8 kf[2][8];
    #pragma unroll
    for (int ks = 0; ks < 2; ++ks)
      #pragma unroll
      for (int js = 0; js < 8; ++js)
        kf[ks][js] = *(const bf16x8*)&Kb[(size_t)((((j0 >> 4) + js) * 8 + ks * 4) * 128) + lane * 8];
    __builtin_amdgcn_sched_barrier(0);

    f32x4 s0[8] = {}, s1[8] = {};
    __builtin_amdgcn_s_setprio(1);
    #pragma unroll
    for (int ks = 0; ks < 2; ++ks) {
      #pragma unroll
      for (int js = 0; js < 8; ++js)
        s0[js] = __builtin_amdgcn_mfma_f32_16x16x32_bf16(kf[ks][js], aq[0][ks], s0[js], 0, 0, 0);
      #pragma unroll
      for (int js = 0; js < 8; ++js)
        s1[js] = __builtin_amdgcn_mfma_f32_16x16x32_bf16(kf[ks][js], aq[1][ks], s1[js], 0, 0, 0);
    }
    __builtin_amdgcn_s_setprio(0);

    // ---- issue ALL 16 V loads now (fenced): exp2/cvt/P-write covers latency
    bf16x8 vf[4][4];
    #pragma unroll
    for (int ks = 0; ks < 4; ++ks)
      #pragma unroll
      for (int ds = 0; ds < 4; ++ds)
        vf[ks][ds] = *(const bf16x8*)&Vb[(size_t)((ds * 256 + (j0 >> 3) + ks * 4) * 128) + lane * 8];
    __builtin_amdgcn_sched_barrier(0);

    // p = exp2(s); pack pairs -> one b64 write per (half, js)
    #pragma unroll
    for (int js = 0; js < 8; ++js) {
      uint2 pk0, pk1;
      pk0.x = cvt_pk_bf16(__builtin_exp2f(s0[js][0]), __builtin_exp2f(s0[js][1]));
      pk0.y = cvt_pk_bf16(__builtin_exp2f(s0[js][2]), __builtin_exp2f(s0[js][3]));
      *(uint2*)&Pw[cl * 136 + js * 16 + quad * 4] = pk0;
      pk1.x = cvt_pk_bf16(__builtin_exp2f(s1[js][0]), __builtin_exp2f(s1[js][1]));
      pk1.y = cvt_pk_bf16(__builtin_exp2f(s1[js][2]), __builtin_exp2f(s1[js][3]));
      *(uint2*)&Pw[(16 + cl) * 136 + js * 16 + quad * 4] = pk1;
    }
    // same-wave LDS write->read ordered by lgkmcnt (no barrier)

    // O += P @ V ; row sums via ones-MFMA on the same A-frags
    __builtin_amdgcn_s_setprio(1);
    #pragma unroll
    for (int ks = 0; ks < 4; ++ks) {
      const bf16x8 ap0 = *(const bf16x8*)&Pw[cl * 136 + ks * 32 + quad * 8];
      const bf16x8 ap1 = *(const bf16x8*)&Pw[(16 + cl) * 136 + ks * 32 + quad * 8];
      psum[0] = __builtin_amdgcn_mfma_f32_16x16x32_bf16(ap0, ones8, psum[0], 0, 0, 0);
      psum[1] = __builtin_amdgcn_mfma_f32_16x16x32_bf16(ap1, ones8, psum[1], 0, 0, 0);
      #pragma unroll
      for (int ds = 0; ds < 4; ++ds) {
        o[0][ds] = __builtin_amdgcn_mfma_f32_16x16x32_bf16(ap0, vf[ks][ds], o[0][ds], 0, 0, 0);
        o[1][ds] = __builtin_amdgcn_mfma_f32_16x16x32_bf16(ap1, vf[ks][ds], o[1][ds], 0, 0, 0);
      }
    }
    __builtin_amdgcn_s_setprio(0);
  }

  // psum rows align with o rows: lane-local normalize, no shuffles
  const int b = bh >> 4, hd = bh & 15;
  #pragma unroll
  for (int h = 0; h < 2; ++h) {
    float inv[4];
    #pragma unroll
    for (int r = 0; r < 4; ++r) inv[r] = __builtin_amdgcn_rcpf(psum[h][r]);
    #pragma unroll
    for (int ds = 0; ds < 4; ++ds)
      #pragma unroll
      for (int r = 0; r < 4; ++r) {
        const int t = q0 + 16 * h + quad * 4 + r;
        const int d = ds * 16 + cl;
        Y[((size_t)b * 2048 + t) * 1024 + hd * 64 + d] = f2bf(o[h][ds][r] * inv[r]);
      }
  }
}

extern "C" void kernel_launch(void* const* d_in, const int* in_sizes, int n_in,
                              void* d_out, int out_size, void* d_ws, size_t ws_size,
                              hipStream_t stream) {
  (void)in_sizes; (void)n_in; (void)out_size; (void)ws_size;
  const float* x  = (const float*)d_in[0];
  const float* Wq = (const float*)d_in[1];
  const float* Wk = (const float*)d_in[2];
  const float* Wv = (const float*)d_in[3];
  const float* Wo = (const float*)d_in[4];

  char* ws = (char*)d_ws;
  const size_t MB = 1024 * 1024;
  u16t* xb  = (u16t*)(ws);               // [4096][1024] bf16 (8 MB) — aliased by Yw
  u16t* Wqb = (u16t*)(ws + 8 * MB);      // Wq/Wk/Wv contiguous -> [3072][1024]
  u16t* Wkb = (u16t*)(ws + 10 * MB);
  u16t* Wvb = (u16t*)(ws + 12 * MB);
  u16t* Wob = (u16t*)(ws + 14 * MB);
  u16t* Qw  = (u16t*)(ws + 16 * MB);     // [32][2048][64] bf16 head-split (pre-scaled)
  u16t* Ktw = (u16t*)(ws + 24 * MB);     // [32] fragment-tiled K'
  u16t* Vtw = (u16t*)(ws + 32 * MB);     // [32] fragment-tiled V'
  u16t* Yw  = xb;                        // safe alias: xb dead after QKV gemm

  convert_bf16<<<8192, 256, 0, stream>>>(x, Wq, Wk, Wv, Wo, xb, Wqb, Wkb, Wvb, Wob);
  // fused QKV: B = [3072][1024], output target selected by n0>>10
  gemm_bt<1, 128><<<dim3(24, 32), 256, 0, stream>>>(
      xb, Wqb, Qw, Ktw, Vtw, 4096, 3072, 1024);
  flash_attn<<<dim3(32, 16), 256, 0, stream>>>(Qw, Ktw, Vtw, Yw);
  // out-proj: BM=64 -> 512 blocks (2/CU) so barrier drains overlap
  gemm_bt<0, 64><<<dim3(8, 64), 256, 0, stream>>>(
      Yw, Wob, d_out, d_out, d_out, 4096, 1024, 1024);
}

// Round 14
// 191.698 us; speedup vs baseline: 1.1615x; 1.0229x over previous
//
#include <hip/hip_runtime.h>
#include <hip/hip_bf16.h>

typedef __attribute__((ext_vector_type(8))) short bf16x8;   // 8 bf16 = 4 VGPRs
typedef __attribute__((ext_vector_type(8))) unsigned short u16x8;
typedef __attribute__((ext_vector_type(4))) float f32x4;
typedef unsigned short u16t;

#define DEVINL static __device__ __forceinline__

DEVINL u16t f2bf(float f) {
  union { __hip_bfloat16 h; u16t u; } cv;
  cv.h = __float2bfloat16(f);
  return cv.u;
}

// packed f32x2 -> bf16x2 (dst.lo = cvt(a), dst.hi = cvt(b)); no builtin on gfx950
DEVINL unsigned cvt_pk_bf16(float a, float b) {
  unsigned r;
  asm("v_cvt_pk_bf16_f32 %0, %1, %2" : "=v"(r) : "v"(a), "v"(b));
  return r;
}

DEVINL void async16(void* lds, const void* g) {
  __builtin_amdgcn_global_load_lds((const __attribute__((address_space(1))) void*)g,
                                   (__attribute__((address_space(3))) void*)lds,
                                   16, 0, 0);
}

// ---------------------------------------------------------------------------
// fp32 -> bf16 conversion + retiling.
// x and Wq/Wk/Wv are written FRAG-TILED:
//   addr(m,k) = ((m>>4)*128 + (k>>3))*128 + (m&15)*8 + (k&7)
// (QKV gemm_fs then loads A/B fragments as direct lane-contiguous b128s,
//  exactly like flash reads Kt/Vt — no LDS staging needed.)
// Wq/Wk/Wv land in ONE contiguous [3072][1024] frag-tiled W' (n global).
// Wo stays LINEAR [1024][1024] (consumed by the staged out-proj gemm).
// Blocks: [0,512) x (mg=blk>>1, half=blk&1); [512,896) W'; [896,1920) Wo rows.
// ---------------------------------------------------------------------------
__global__ __launch_bounds__(256) void convert_bf16(
    const float* __restrict__ x,  const float* __restrict__ wq,
    const float* __restrict__ wk, const float* __restrict__ wv,
    const float* __restrict__ wo,
    u16t* __restrict__ xb, u16t* __restrict__ wqb, u16t* __restrict__ wob) {
  const int blk = blockIdx.x;
  const int tid = threadIdx.x;
  if (blk < 896) {
    // frag-tiling path: 16 rows x 512 k per block (64 chunks)
    const int lane = tid & 63, w = tid >> 6;
    const int r = lane & 15, cw = lane >> 4;
    int mg, half, row0;
    const float* src; u16t* dst;
    if (blk < 512) { mg = blk >> 1; half = blk & 1; src = x; dst = xb; row0 = mg * 16; }
    else {
      const int wblk = blk - 512;
      mg = wblk >> 1; half = wblk & 1; dst = wqb;
      const int n0 = mg * 16;
      if (n0 < 1024)      { src = wq; row0 = n0; }
      else if (n0 < 2048) { src = wk; row0 = n0 - 1024; }
      else                { src = wv; row0 = n0 - 2048; }
    }
    #pragma unroll
    for (int ic = 0; ic < 4; ++ic) {
      const int c2 = half * 64 + w * 16 + ic * 4 + cw;   // chunk = k>>3
      const float4 v0 = *(const float4*)&src[(size_t)(row0 + r) * 1024 + c2 * 8];
      const float4 v1 = *(const float4*)&src[(size_t)(row0 + r) * 1024 + c2 * 8 + 4];
      u16x8 o;
      o[0] = f2bf(v0.x); o[1] = f2bf(v0.y); o[2] = f2bf(v0.z); o[3] = f2bf(v0.w);
      o[4] = f2bf(v1.x); o[5] = f2bf(v1.y); o[6] = f2bf(v1.z); o[7] = f2bf(v1.w);
      *(u16x8*)&dst[((size_t)mg * 128 + c2) * 128 + r * 8] = o;   // wave: 1KB contig
    }
  } else {
    // Wo linear path (row per block)
    const int row = blk - 896;
    const size_t i = (size_t)row * 1024 + (size_t)tid * 4;
    const float4 v = *(const float4*)&wo[i];
    ushort4 rr;
    rr.x = f2bf(v.x); rr.y = f2bf(v.y); rr.z = f2bf(v.z); rr.w = f2bf(v.w);
    *(ushort4*)&wob[i] = rr;
  }
}

// ---------------------------------------------------------------------------
// QKV GEMM, flash-style frag-streaming: ZERO LDS, ZERO barriers.
// C[m,n] = sum_k A'[m,k]*B'[n,k], A'/B' FRAG-TILED (see convert).
// Grid (24 n-strips, 32 m-strips), 256 thr = 4 waves, wave tile 64x64.
// Per BK=32 panel: 8 direct b128 frag loads (lane-contiguous by layout
// construction) + 16 MFMA. Latency hidden by TLP (3 blocks/CU, 12 waves/CU)
// -- same structure that carries flash at ~1.1 PF effective.
// n-strip on grid.x (24%8==0): id%8 = n%8 pins each XCD to 3 B-strips
// (768 KB, L2-resident); A streams from L3.
// launch_bounds (256,4): cap 128 VGPR (demand ~116, no spill; R12 lesson).
// Epilogue identical to old MODE1 (same acc/lane geometry).
// ---------------------------------------------------------------------------
__global__ __launch_bounds__(256, 4) void gemm_fs(
    const u16t* __restrict__ A, const u16t* __restrict__ B,
    void* __restrict__ C0, void* __restrict__ C1, void* __restrict__ C2) {
  const int tid = threadIdx.x;
  const int lane = tid & 63;
  const int w = tid >> 6;
  const int wm = w >> 1, wn = w & 1;
  const int quad = lane >> 4, cl = lane & 15;
  const int m0 = blockIdx.y * 128;
  const int n0 = blockIdx.x * 128;

  // frag base: row-group ((m0>>4)+wm*4+i), chunk kp*4+quad, elem cl*8
  const u16t* Ap = A + ((size_t)((m0 >> 4) + wm * 4) * 128 + quad) * 128 + cl * 8;
  const u16t* Bp = B + ((size_t)((n0 >> 4) + wn * 4) * 128 + quad) * 128 + cl * 8;

  f32x4 acc[4][4] = {};
  #pragma unroll 1
  for (int kp = 0; kp < 32; ++kp) {
    bf16x8 af[4], bfr[4];
    #pragma unroll
    for (int i = 0; i < 4; ++i)
      af[i] = *(const bf16x8*)&Ap[(size_t)i * 16384 + kp * 512];
    #pragma unroll
    for (int j = 0; j < 4; ++j)
      bfr[j] = *(const bf16x8*)&Bp[(size_t)j * 16384 + kp * 512];
    #pragma unroll
    for (int i = 0; i < 4; ++i)
      #pragma unroll
      for (int j = 0; j < 4; ++j)
        acc[i][j] = __builtin_amdgcn_mfma_f32_16x16x32_bf16(af[i], bfr[j], acc[i][j], 0, 0, 0);
  }

  const int nz = n0 >> 10;           // weight id (block-uniform)
  #pragma unroll
  for (int i = 0; i < 4; ++i)
    #pragma unroll
    for (int j = 0; j < 4; ++j) {
      const int mb = m0 + wm * 64 + i * 16 + quad * 4;   // 4 consecutive m (t)
      const int n  = n0 + wn * 64 + j * 16 + cl;
      const int nw = n & 1023, h = nw >> 6, d = nw & 63;
      const int b = mb >> 11, tb = mb & 2047;
      const size_t bh = (size_t)(b * 16 + h);
      if (nz == 2) {
        ushort4 v4;
        v4.x = f2bf(acc[i][j][0]); v4.y = f2bf(acc[i][j][1]);
        v4.z = f2bf(acc[i][j][2]); v4.w = f2bf(acc[i][j][3]);
        const size_t addr = (bh << 17) +
            (size_t)(((d >> 4) * 256 + (tb >> 3)) * 128 + (d & 15) * 8 + (tb & 7));
        *(ushort4*)&((u16t*)C2)[addr] = v4;
      } else if (nz == 1) {
        const size_t basea = (bh << 17) +
            (size_t)(((tb >> 4) * 8 + (d >> 3)) * 128 + (d & 7));
        #pragma unroll
        for (int r = 0; r < 4; ++r)
          ((u16t*)C1)[basea + ((tb & 15) + r) * 8] = f2bf(acc[i][j][r]);
      } else {
        // Q: pre-scale by 0.125/ln2 so flash softmax is p = exp2(s)
        #pragma unroll
        for (int r = 0; r < 4; ++r)
          ((u16t*)C0)[(bh * 2048 + tb + r) * 64 + d] =
              f2bf(acc[i][j][r] * 0.18033688011112043f);
      }
    }
}

// ---------------------------------------------------------------------------
// Out-proj GEMM (staged m97-structure, unchanged): C = A@B^T, A/B LINEAR.
// Tile BM x 128; BM=64 -> 2 blocks/CU (R7 win). Cross-panel dbuf (R10).
// ---------------------------------------------------------------------------
template <int MODE, int BM>
__global__ __launch_bounds__(256) void gemm_bt(
    const u16t* __restrict__ A, const u16t* __restrict__ B,
    void* __restrict__ C0, void* __restrict__ C1, void* __restrict__ C2,
    int M, int N, int K) {
  constexpr int MI = BM / 32;
  __shared__ u16t As[2][BM * 32];
  __shared__ u16t Bs[2][128 * 32];

  const int tid = threadIdx.x;
  const int lane = tid & 63;
  const int w = tid >> 6;
  const int wm = w >> 1, wn = w & 1;
  const int quad = lane >> 4, cl = lane & 15;
  const int m0 = blockIdx.y * BM;
  const int n0 = blockIdx.x * 128;

  const int srow = lane >> 2;
  const int scol = (lane & 3) * 8;

  f32x4 acc[MI][4] = {};

  #define STAGEP(b, kp)                                                       \
    {                                                                         \
      _Pragma("unroll")                                                       \
      for (int ii = 0; ii < BM / 64; ++ii) {                                  \
        const int c = w + ii * 4;                                             \
        async16(&As[b][c * 512],                                              \
                &A[(size_t)(m0 + c * 16 + srow) * K + (kp) * 32 + scol]);     \
      }                                                                       \
      _Pragma("unroll")                                                       \
      for (int ii = 0; ii < 2; ++ii) {                                        \
        const int c = w + ii * 4;                                             \
        async16(&Bs[b][c * 512],                                              \
                &B[(size_t)(n0 + c * 16 + srow) * K + (kp) * 32 + scol]);     \
      }                                                                       \
    }

  #define COMPUTEP(b)                                                         \
    {                                                                         \
      bf16x8 af[MI], bfr[4];                                                  \
      _Pragma("unroll")                                                       \
      for (int i = 0; i < MI; ++i)                                            \
        af[i] = *(const bf16x8*)&As[b][(wm * (BM / 2) + i * 16 + cl) * 32 + quad * 8]; \
      _Pragma("unroll")                                                       \
      for (int j = 0; j < 4; ++j)                                             \
        bfr[j] = *(const bf16x8*)&Bs[b][(wn * 64 + j * 16 + cl) * 32 + quad * 8]; \
      _Pragma("unroll")                                                       \
      for (int i = 0; i < MI; ++i)                                            \
        _Pragma("unroll")                                                     \
        for (int j = 0; j < 4; ++j)                                           \
          acc[i][j] = __builtin_amdgcn_mfma_f32_16x16x32_bf16(af[i], bfr[j], acc[i][j], 0, 0, 0); \
    }

  const int NP = K >> 5;
  STAGEP(0, 0);
  __syncthreads();
  for (int kp = 0; kp < NP; kp += 2) {
    if (kp + 1 < NP) STAGEP(1, kp + 1);
    COMPUTEP(0);
    __syncthreads();
    if (kp + 2 < NP) STAGEP(0, kp + 2);
    COMPUTEP(1);
    __syncthreads();
  }
  #undef STAGEP
  #undef COMPUTEP

  #pragma unroll
  for (int i = 0; i < MI; ++i)
    #pragma unroll
    for (int j = 0; j < 4; ++j) {
      const int mb = m0 + wm * (BM / 2) + i * 16 + quad * 4;
      const int n  = n0 + wn * 64 + j * 16 + cl;
      if (MODE == 0) {
        #pragma unroll
        for (int r = 0; r < 4; ++r)
          ((float*)C0)[(size_t)(mb + r) * N + n] = acc[i][j][r];
      }
      (void)C1; (void)C2;
    }
}

// ---------------------------------------------------------------------------
// Flash attention (R13, measured 62.4-62.7us, VGPR 100, no spill) — FINAL.
// Grid (x=32 bh, y=16 q-chunks), block 256 = 4 independent barrier-free
// waves; wave owns 32 q-rows; bh-pinned XCDs; fenced K/V load hoisting;
// swapped QK^T; ones-MFMA row sums; lane-local normalize; setprio (neutral,
// kept).
// ---------------------------------------------------------------------------
__global__ __launch_bounds__(256, 2) void flash_attn(
    const u16t* __restrict__ Q, const u16t* __restrict__ Kt,
    const u16t* __restrict__ Vt, u16t* __restrict__ Y) {
  __shared__ u16t Ps[4 * 32 * 136];   // per-wave 32-row P scratch (34.8 KB)
  const int tid = threadIdx.x;
  const int lane = tid & 63;
  const int w = tid >> 6;
  const int quad = lane >> 4, cl = lane & 15;
  const int bh = blockIdx.x;          // bh on x: id%8==bh%8 pins bh to one XCD
  const int q0 = blockIdx.y * 128 + w * 32;
  const u16t* Kb = Kt + ((size_t)bh << 17);
  const u16t* Vb = Vt + ((size_t)bh << 17);

  bf16x8 aq[2][2];
  #pragma unroll
  for (int h = 0; h < 2; ++h)
    #pragma unroll
    for (int ks = 0; ks < 2; ++ks)
      aq[h][ks] = *(const bf16x8*)&Q[((size_t)bh * 2048 + q0 + 16 * h + cl) * 64 + ks * 32 + quad * 8];

  bf16x8 ones8;
  #pragma unroll
  for (int i = 0; i < 8; ++i) ones8[i] = (short)0x3F80;

  f32x4 o[2][4] = {};
  f32x4 psum[2] = {};

  u16t* Pw = &Ps[w * 32 * 136];

  for (int jt = 0; jt < 16; ++jt) {
    const int j0 = jt * 128;

    bf16x8 kf[2][8];
    #pragma unroll
    for (int ks = 0; ks < 2; ++ks)
      #pragma unroll
      for (int js = 0; js < 8; ++js)
        kf[ks][js] = *(const bf16x8*)&Kb[(size_t)((((j0 >> 4) + js) * 8 + ks * 4) * 128) + lane * 8];
    __builtin_amdgcn_sched_barrier(0);

    f32x4 s0[8] = {}, s1[8] = {};
    __builtin_amdgcn_s_setprio(1);
    #pragma unroll
    for (int ks = 0; ks < 2; ++ks) {
      #pragma unroll
      for (int js = 0; js < 8; ++js)
        s0[js] = __builtin_amdgcn_mfma_f32_16x16x32_bf16(kf[ks][js], aq[0][ks], s0[js], 0, 0, 0);
      #pragma unroll
      for (int js = 0; js < 8; ++js)
        s1[js] = __builtin_amdgcn_mfma_f32_16x16x32_bf16(kf[ks][js], aq[1][ks], s1[js], 0, 0, 0);
    }
    __builtin_amdgcn_s_setprio(0);

    bf16x8 vf[4][4];
    #pragma unroll
    for (int ks = 0; ks < 4; ++ks)
      #pragma unroll
      for (int ds = 0; ds < 4; ++ds)
        vf[ks][ds] = *(const bf16x8*)&Vb[(size_t)((ds * 256 + (j0 >> 3) + ks * 4) * 128) + lane * 8];
    __builtin_amdgcn_sched_barrier(0);

    #pragma unroll
    for (int js = 0; js < 8; ++js) {
      uint2 pk0, pk1;
      pk0.x = cvt_pk_bf16(__builtin_exp2f(s0[js][0]), __builtin_exp2f(s0[js][1]));
      pk0.y = cvt_pk_bf16(__builtin_exp2f(s0[js][2]), __builtin_exp2f(s0[js][3]));
      *(uint2*)&Pw[cl * 136 + js * 16 + quad * 4] = pk0;
      pk1.x = cvt_pk_bf16(__builtin_exp2f(s1[js][0]), __builtin_exp2f(s1[js][1]));
      pk1.y = cvt_pk_bf16(__builtin_exp2f(s1[js][2]), __builtin_exp2f(s1[js][3]));
      *(uint2*)&Pw[(16 + cl) * 136 + js * 16 + quad * 4] = pk1;
    }
    // same-wave LDS write->read ordered by lgkmcnt (no barrier)

    __builtin_amdgcn_s_setprio(1);
    #pragma unroll
    for (int ks = 0; ks < 4; ++ks) {
      const bf16x8 ap0 = *(const bf16x8*)&Pw[cl * 136 + ks * 32 + quad * 8];
      const bf16x8 ap1 = *(const bf16x8*)&Pw[(16 + cl) * 136 + ks * 32 + quad * 8];
      psum[0] = __builtin_amdgcn_mfma_f32_16x16x32_bf16(ap0, ones8, psum[0], 0, 0, 0);
      psum[1] = __builtin_amdgcn_mfma_f32_16x16x32_bf16(ap1, ones8, psum[1], 0, 0, 0);
      #pragma unroll
      for (int ds = 0; ds < 4; ++ds) {
        o[0][ds] = __builtin_amdgcn_mfma_f32_16x16x32_bf16(ap0, vf[ks][ds], o[0][ds], 0, 0, 0);
        o[1][ds] = __builtin_amdgcn_mfma_f32_16x16x32_bf16(ap1, vf[ks][ds], o[1][ds], 0, 0, 0);
      }
    }
    __builtin_amdgcn_s_setprio(0);
  }

  const int b = bh >> 4, hd = bh & 15;
  #pragma unroll
  for (int h = 0; h < 2; ++h) {
    float inv[4];
    #pragma unroll
    for (int r = 0; r < 4; ++r) inv[r] = __builtin_amdgcn_rcpf(psum[h][r]);
    #pragma unroll
    for (int ds = 0; ds < 4; ++ds)
      #pragma unroll
      for (int r = 0; r < 4; ++r) {
        const int t = q0 + 16 * h + quad * 4 + r;
        const int d = ds * 16 + cl;
        Y[((size_t)b * 2048 + t) * 1024 + hd * 64 + d] = f2bf(o[h][ds][r] * inv[r]);
      }
  }
}

extern "C" void kernel_launch(void* const* d_in, const int* in_sizes, int n_in,
                              void* d_out, int out_size, void* d_ws, size_t ws_size,
                              hipStream_t stream) {
  (void)in_sizes; (void)n_in; (void)out_size; (void)ws_size;
  const float* x  = (const float*)d_in[0];
  const float* Wq = (const float*)d_in[1];
  const float* Wk = (const float*)d_in[2];
  const float* Wv = (const float*)d_in[3];
  const float* Wo = (const float*)d_in[4];

  char* ws = (char*)d_ws;
  const size_t MB = 1024 * 1024;
  u16t* xb  = (u16t*)(ws);               // [4096][1024] FRAG-TILED bf16 (8 MB); aliased by Yw
  u16t* Wqb = (u16t*)(ws + 8 * MB);      // W' [3072][1024] FRAG-TILED (Wq/Wk/Wv contiguous)
  u16t* Wob = (u16t*)(ws + 14 * MB);     // Wo LINEAR [1024][1024]
  u16t* Qw  = (u16t*)(ws + 16 * MB);     // [32][2048][64] bf16 head-split (pre-scaled)
  u16t* Ktw = (u16t*)(ws + 24 * MB);     // [32] fragment-tiled K'
  u16t* Vtw = (u16t*)(ws + 32 * MB);     // [32] fragment-tiled V'
  u16t* Yw  = xb;                        // safe alias: xb dead after QKV gemm

  convert_bf16<<<1920, 256, 0, stream>>>(x, Wq, Wk, Wv, Wo, xb, Wqb, Wob);
  // fused QKV, frag-streaming (barrier-free, zero LDS)
  gemm_fs<<<dim3(24, 32), 256, 0, stream>>>(xb, Wqb, Qw, Ktw, Vtw);
  flash_attn<<<dim3(32, 16), 256, 0, stream>>>(Qw, Ktw, Vtw, Yw);
  // out-proj: staged gemm, BM=64 -> 2 blocks/CU
  gemm_bt<0, 64><<<dim3(8, 64), 256, 0, stream>>>(
      Yw, Wob, d_out, d_out, d_out, 4096, 1024, 1024);
}

// Round 15
// 189.281 us; speedup vs baseline: 1.1763x; 1.0128x over previous
//
#include <hip/hip_runtime.h>
#include <hip/hip_bf16.h>

typedef __attribute__((ext_vector_type(8))) short bf16x8;   // 8 bf16 = 4 VGPRs
typedef __attribute__((ext_vector_type(8))) unsigned short u16x8;
typedef __attribute__((ext_vector_type(4))) float f32x4;
typedef unsigned short u16t;

#define DEVINL static __device__ __forceinline__

DEVINL u16t f2bf(float f) {
  union { __hip_bfloat16 h; u16t u; } cv;
  cv.h = __float2bfloat16(f);
  return cv.u;
}

// packed f32x2 -> bf16x2 (dst.lo = cvt(a), dst.hi = cvt(b)); no builtin on gfx950
DEVINL unsigned cvt_pk_bf16(float a, float b) {
  unsigned r;
  asm("v_cvt_pk_bf16_f32 %0, %1, %2" : "=v"(r) : "v"(a), "v"(b));
  return r;
}

DEVINL void async16(void* lds, const void* g) {
  __builtin_amdgcn_global_load_lds((const __attribute__((address_space(1))) void*)g,
                                   (__attribute__((address_space(3))) void*)lds,
                                   16, 0, 0);
}

// ---------------------------------------------------------------------------
// fp32 -> bf16 conversion + retiling (unchanged from R14).
// x and Wq/Wk/Wv written FRAG-TILED:
//   addr(m,k) = ((m>>4)*128 + (k>>3))*128 + (m&15)*8 + (k&7)
// Wo stays LINEAR. Blocks: [0,512) x; [512,896) W'; [896,1920) Wo rows.
// ---------------------------------------------------------------------------
__global__ __launch_bounds__(256) void convert_bf16(
    const float* __restrict__ x,  const float* __restrict__ wq,
    const float* __restrict__ wk, const float* __restrict__ wv,
    const float* __restrict__ wo,
    u16t* __restrict__ xb, u16t* __restrict__ wqb, u16t* __restrict__ wob) {
  const int blk = blockIdx.x;
  const int tid = threadIdx.x;
  if (blk < 896) {
    const int lane = tid & 63, w = tid >> 6;
    const int r = lane & 15, cw = lane >> 4;
    int mg, half, row0;
    const float* src; u16t* dst;
    if (blk < 512) { mg = blk >> 1; half = blk & 1; src = x; dst = xb; row0 = mg * 16; }
    else {
      const int wblk = blk - 512;
      mg = wblk >> 1; half = wblk & 1; dst = wqb;
      const int n0 = mg * 16;
      if (n0 < 1024)      { src = wq; row0 = n0; }
      else if (n0 < 2048) { src = wk; row0 = n0 - 1024; }
      else                { src = wv; row0 = n0 - 2048; }
    }
    #pragma unroll
    for (int ic = 0; ic < 4; ++ic) {
      const int c2 = half * 64 + w * 16 + ic * 4 + cw;   // chunk = k>>3
      const float4 v0 = *(const float4*)&src[(size_t)(row0 + r) * 1024 + c2 * 8];
      const float4 v1 = *(const float4*)&src[(size_t)(row0 + r) * 1024 + c2 * 8 + 4];
      u16x8 o;
      o[0] = f2bf(v0.x); o[1] = f2bf(v0.y); o[2] = f2bf(v0.z); o[3] = f2bf(v0.w);
      o[4] = f2bf(v1.x); o[5] = f2bf(v1.y); o[6] = f2bf(v1.z); o[7] = f2bf(v1.w);
      *(u16x8*)&dst[((size_t)mg * 128 + c2) * 128 + r * 8] = o;   // wave: 1KB contig
    }
  } else {
    const int row = blk - 896;
    const size_t i = (size_t)row * 1024 + (size_t)tid * 4;
    const float4 v = *(const float4*)&wo[i];
    ushort4 rr;
    rr.x = f2bf(v.x); rr.y = f2bf(v.y); rr.z = f2bf(v.z); rr.w = f2bf(v.w);
    *(ushort4*)&wob[i] = rr;
  }
}

// ---------------------------------------------------------------------------
// QKV GEMM V2: frag-streaming + PANEL REGISTER DOUBLE-BUFFER (R9 pattern).
// Zero LDS, zero barriers. Per BK=32 panel: 8 direct b128 frag loads + 16
// MFMA; panel kp+1's loads issue BEFORE panel kp's MFMAs (fenced) -> MFMAs
// wait on counted vmcnt(8) while next panel flies under MFMA issue + the
// staggered co-resident waves. R14's unroll-1 loop paid a full L2/L3 round
// trip per panel (the identified ~65us pathology).
// Register budget: acc 64 + 2 frag sets 64 + bases ~12 = ~145 <= 170
// (3 waves/SIMD cap; launch_bounds(256,3) matches the 3-blocks/CU grid).
// Spill tripwire: any non-flash WRITE_SIZE jump -> revert.
// n-strip on grid.x (24%8==0): per-XCD B slice 768 KB L2-resident.
// ---------------------------------------------------------------------------
__global__ __launch_bounds__(256, 3) void gemm_fs(
    const u16t* __restrict__ A, const u16t* __restrict__ B,
    void* __restrict__ C0, void* __restrict__ C1, void* __restrict__ C2) {
  const int tid = threadIdx.x;
  const int lane = tid & 63;
  const int w = tid >> 6;
  const int wm = w >> 1, wn = w & 1;
  const int quad = lane >> 4, cl = lane & 15;
  const int m0 = blockIdx.y * 128;
  const int n0 = blockIdx.x * 128;

  // frag base: row-group ((m0>>4)+wm*4+i), chunk kp*4+quad, elem cl*8
  const u16t* Ap = A + ((size_t)((m0 >> 4) + wm * 4) * 128 + quad) * 128 + cl * 8;
  const u16t* Bp = B + ((size_t)((n0 >> 4) + wn * 4) * 128 + quad) * 128 + cl * 8;

  f32x4 acc[4][4] = {};
  bf16x8 afA[4], bfA[4], afB[4], bfB[4];

  #define LOADP(af_, bf_, kp_)                                                \
    {                                                                         \
      _Pragma("unroll")                                                       \
      for (int i = 0; i < 4; ++i)                                             \
        af_[i] = *(const bf16x8*)&Ap[(size_t)i * 16384 + (kp_) * 512];        \
      _Pragma("unroll")                                                       \
      for (int j = 0; j < 4; ++j)                                             \
        bf_[j] = *(const bf16x8*)&Bp[(size_t)j * 16384 + (kp_) * 512];        \
    }

  #define MFMAP(af_, bf_)                                                     \
    {                                                                         \
      _Pragma("unroll")                                                       \
      for (int i = 0; i < 4; ++i)                                             \
        _Pragma("unroll")                                                     \
        for (int j = 0; j < 4; ++j)                                           \
          acc[i][j] = __builtin_amdgcn_mfma_f32_16x16x32_bf16(af_[i], bf_[j], acc[i][j], 0, 0, 0); \
    }

  LOADP(afA, bfA, 0);
  __builtin_amdgcn_sched_barrier(0);
  #pragma unroll 1
  for (int kp = 0; kp < 32; kp += 2) {
    LOADP(afB, bfB, kp + 1);          // prefetch odd panel (kp+1 <= 31 always)
    __builtin_amdgcn_sched_barrier(0);
    MFMAP(afA, bfA);                  // counted wait: afB/bfB stay in flight
    if (kp + 2 < 32) LOADP(afA, bfA, kp + 2);
    __builtin_amdgcn_sched_barrier(0);
    MFMAP(afB, bfB);
  }
  #undef LOADP
  #undef MFMAP

  const int nz = n0 >> 10;           // weight id (block-uniform)
  #pragma unroll
  for (int i = 0; i < 4; ++i)
    #pragma unroll
    for (int j = 0; j < 4; ++j) {
      const int mb = m0 + wm * 64 + i * 16 + quad * 4;   // 4 consecutive m (t)
      const int n  = n0 + wn * 64 + j * 16 + cl;
      const int nw = n & 1023, h = nw >> 6, d = nw & 63;
      const int b = mb >> 11, tb = mb & 2047;
      const size_t bh = (size_t)(b * 16 + h);
      if (nz == 2) {
        ushort4 v4;
        v4.x = f2bf(acc[i][j][0]); v4.y = f2bf(acc[i][j][1]);
        v4.z = f2bf(acc[i][j][2]); v4.w = f2bf(acc[i][j][3]);
        const size_t addr = (bh << 17) +
            (size_t)(((d >> 4) * 256 + (tb >> 3)) * 128 + (d & 15) * 8 + (tb & 7));
        *(ushort4*)&((u16t*)C2)[addr] = v4;
      } else if (nz == 1) {
        const size_t basea = (bh << 17) +
            (size_t)(((tb >> 4) * 8 + (d >> 3)) * 128 + (d & 7));
        #pragma unroll
        for (int r = 0; r < 4; ++r)
          ((u16t*)C1)[basea + ((tb & 15) + r) * 8] = f2bf(acc[i][j][r]);
      } else {
        // Q: pre-scale by 0.125/ln2 so flash softmax is p = exp2(s)
        #pragma unroll
        for (int r = 0; r < 4; ++r)
          ((u16t*)C0)[(bh * 2048 + tb + r) * 64 + d] =
              f2bf(acc[i][j][r] * 0.18033688011112043f);
      }
    }
}

// ---------------------------------------------------------------------------
// Out-proj GEMM (staged m97-structure, unchanged): C = A@B^T, A/B LINEAR.
// Tile BM x 128; BM=64 -> 2 blocks/CU (R7 win). Cross-panel dbuf (R10).
// ---------------------------------------------------------------------------
template <int MODE, int BM>
__global__ __launch_bounds__(256) void gemm_bt(
    const u16t* __restrict__ A, const u16t* __restrict__ B,
    void* __restrict__ C0, void* __restrict__ C1, void* __restrict__ C2,
    int M, int N, int K) {
  constexpr int MI = BM / 32;
  __shared__ u16t As[2][BM * 32];
  __shared__ u16t Bs[2][128 * 32];

  const int tid = threadIdx.x;
  const int lane = tid & 63;
  const int w = tid >> 6;
  const int wm = w >> 1, wn = w & 1;
  const int quad = lane >> 4, cl = lane & 15;
  const int m0 = blockIdx.y * BM;
  const int n0 = blockIdx.x * 128;

  const int srow = lane >> 2;
  const int scol = (lane & 3) * 8;

  f32x4 acc[MI][4] = {};

  #define STAGEP(b, kp)                                                       \
    {                                                                         \
      _Pragma("unroll")                                                       \
      for (int ii = 0; ii < BM / 64; ++ii) {                                  \
        const int c = w + ii * 4;                                             \
        async16(&As[b][c * 512],                                              \
                &A[(size_t)(m0 + c * 16 + srow) * K + (kp) * 32 + scol]);     \
      }                                                                       \
      _Pragma("unroll")                                                       \
      for (int ii = 0; ii < 2; ++ii) {                                        \
        const int c = w + ii * 4;                                             \
        async16(&Bs[b][c * 512],                                              \
                &B[(size_t)(n0 + c * 16 + srow) * K + (kp) * 32 + scol]);     \
      }                                                                       \
    }

  #define COMPUTEP(b)                                                         \
    {                                                                         \
      bf16x8 af[MI], bfr[4];                                                  \
      _Pragma("unroll")                                                       \
      for (int i = 0; i < MI; ++i)                                            \
        af[i] = *(const bf16x8*)&As[b][(wm * (BM / 2) + i * 16 + cl) * 32 + quad * 8]; \
      _Pragma("unroll")                                                       \
      for (int j = 0; j < 4; ++j)                                             \
        bfr[j] = *(const bf16x8*)&Bs[b][(wn * 64 + j * 16 + cl) * 32 + quad * 8]; \
      _Pragma("unroll")                                                       \
      for (int i = 0; i < MI; ++i)                                            \
        _Pragma("unroll")                                                     \
        for (int j = 0; j < 4; ++j)                                           \
          acc[i][j] = __builtin_amdgcn_mfma_f32_16x16x32_bf16(af[i], bfr[j], acc[i][j], 0, 0, 0); \
    }

  const int NP = K >> 5;
  STAGEP(0, 0);
  __syncthreads();
  for (int kp = 0; kp < NP; kp += 2) {
    if (kp + 1 < NP) STAGEP(1, kp + 1);
    COMPUTEP(0);
    __syncthreads();
    if (kp + 2 < NP) STAGEP(0, kp + 2);
    COMPUTEP(1);
    __syncthreads();
  }
  #undef STAGEP
  #undef COMPUTEP

  #pragma unroll
  for (int i = 0; i < MI; ++i)
    #pragma unroll
    for (int j = 0; j < 4; ++j) {
      const int mb = m0 + wm * (BM / 2) + i * 16 + quad * 4;
      const int n  = n0 + wn * 64 + j * 16 + cl;
      if (MODE == 0) {
        #pragma unroll
        for (int r = 0; r < 4; ++r)
          ((float*)C0)[(size_t)(mb + r) * N + n] = acc[i][j][r];
      }
      (void)C1; (void)C2;
    }
}

// ---------------------------------------------------------------------------
// Flash attention (R13, measured 62.0-62.7us, VGPR 100, no spill) — FINAL.
// ---------------------------------------------------------------------------
__global__ __launch_bounds__(256, 2) void flash_attn(
    const u16t* __restrict__ Q, const u16t* __restrict__ Kt,
    const u16t* __restrict__ Vt, u16t* __restrict__ Y) {
  __shared__ u16t Ps[4 * 32 * 136];   // per-wave 32-row P scratch (34.8 KB)
  const int tid = threadIdx.x;
  const int lane = tid & 63;
  const int w = tid >> 6;
  const int quad = lane >> 4, cl = lane & 15;
  const int bh = blockIdx.x;          // bh on x: id%8==bh%8 pins bh to one XCD
  const int q0 = blockIdx.y * 128 + w * 32;
  const u16t* Kb = Kt + ((size_t)bh << 17);
  const u16t* Vb = Vt + ((size_t)bh << 17);

  bf16x8 aq[2][2];
  #pragma unroll
  for (int h = 0; h < 2; ++h)
    #pragma unroll
    for (int ks = 0; ks < 2; ++ks)
      aq[h][ks] = *(const bf16x8*)&Q[((size_t)bh * 2048 + q0 + 16 * h + cl) * 64 + ks * 32 + quad * 8];

  bf16x8 ones8;
  #pragma unroll
  for (int i = 0; i < 8; ++i) ones8[i] = (short)0x3F80;

  f32x4 o[2][4] = {};
  f32x4 psum[2] = {};

  u16t* Pw = &Ps[w * 32 * 136];

  for (int jt = 0; jt < 16; ++jt) {
    const int j0 = jt * 128;

    bf16x8 kf[2][8];
    #pragma unroll
    for (int ks = 0; ks < 2; ++ks)
      #pragma unroll
      for (int js = 0; js < 8; ++js)
        kf[ks][js] = *(const bf16x8*)&Kb[(size_t)((((j0 >> 4) + js) * 8 + ks * 4) * 128) + lane * 8];
    __builtin_amdgcn_sched_barrier(0);

    f32x4 s0[8] = {}, s1[8] = {};
    __builtin_amdgcn_s_setprio(1);
    #pragma unroll
    for (int ks = 0; ks < 2; ++ks) {
      #pragma unroll
      for (int js = 0; js < 8; ++js)
        s0[js] = __builtin_amdgcn_mfma_f32_16x16x32_bf16(kf[ks][js], aq[0][ks], s0[js], 0, 0, 0);
      #pragma unroll
      for (int js = 0; js < 8; ++js)
        s1[js] = __builtin_amdgcn_mfma_f32_16x16x32_bf16(kf[ks][js], aq[1][ks], s1[js], 0, 0, 0);
    }
    __builtin_amdgcn_s_setprio(0);

    bf16x8 vf[4][4];
    #pragma unroll
    for (int ks = 0; ks < 4; ++ks)
      #pragma unroll
      for (int ds = 0; ds < 4; ++ds)
        vf[ks][ds] = *(const bf16x8*)&Vb[(size_t)((ds * 256 + (j0 >> 3) + ks * 4) * 128) + lane * 8];
    __builtin_amdgcn_sched_barrier(0);

    #pragma unroll
    for (int js = 0; js < 8; ++js) {
      uint2 pk0, pk1;
      pk0.x = cvt_pk_bf16(__builtin_exp2f(s0[js][0]), __builtin_exp2f(s0[js][1]));
      pk0.y = cvt_pk_bf16(__builtin_exp2f(s0[js][2]), __builtin_exp2f(s0[js][3]));
      *(uint2*)&Pw[cl * 136 + js * 16 + quad * 4] = pk0;
      pk1.x = cvt_pk_bf16(__builtin_exp2f(s1[js][0]), __builtin_exp2f(s1[js][1]));
      pk1.y = cvt_pk_bf16(__builtin_exp2f(s1[js][2]), __builtin_exp2f(s1[js][3]));
      *(uint2*)&Pw[(16 + cl) * 136 + js * 16 + quad * 4] = pk1;
    }
    // same-wave LDS write->read ordered by lgkmcnt (no barrier)

    __builtin_amdgcn_s_setprio(1);
    #pragma unroll
    for (int ks = 0; ks < 4; ++ks) {
      const bf16x8 ap0 = *(const bf16x8*)&Pw[cl * 136 + ks * 32 + quad * 8];
      const bf16x8 ap1 = *(const bf16x8*)&Pw[(16 + cl) * 136 + ks * 32 + quad * 8];
      psum[0] = __builtin_amdgcn_mfma_f32_16x16x32_bf16(ap0, ones8, psum[0], 0, 0, 0);
      psum[1] = __builtin_amdgcn_mfma_f32_16x16x32_bf16(ap1, ones8, psum[1], 0, 0, 0);
      #pragma unroll
      for (int ds = 0; ds < 4; ++ds) {
        o[0][ds] = __builtin_amdgcn_mfma_f32_16x16x32_bf16(ap0, vf[ks][ds], o[0][ds], 0, 0, 0);
        o[1][ds] = __builtin_amdgcn_mfma_f32_16x16x32_bf16(ap1, vf[ks][ds], o[1][ds], 0, 0, 0);
      }
    }
    __builtin_amdgcn_s_setprio(0);
  }

  const int b = bh >> 4, hd = bh & 15;
  #pragma unroll
  for (int h = 0; h < 2; ++h) {
    float inv[4];
    #pragma unroll
    for (int r = 0; r < 4; ++r) inv[r] = __builtin_amdgcn_rcpf(psum[h][r]);
    #pragma unroll
    for (int ds = 0; ds < 4; ++ds)
      #pragma unroll
      for (int r = 0; r < 4; ++r) {
        const int t = q0 + 16 * h + quad * 4 + r;
        const int d = ds * 16 + cl;
        Y[((size_t)b * 2048 + t) * 1024 + hd * 64 + d] = f2bf(o[h][ds][r] * inv[r]);
      }
  }
}

extern "C" void kernel_launch(void* const* d_in, const int* in_sizes, int n_in,
                              void* d_out, int out_size, void* d_ws, size_t ws_size,
                              hipStream_t stream) {
  (void)in_sizes; (void)n_in; (void)out_size; (void)ws_size;
  const float* x  = (const float*)d_in[0];
  const float* Wq = (const float*)d_in[1];
  const float* Wk = (const float*)d_in[2];
  const float* Wv = (const float*)d_in[3];
  const float* Wo = (const float*)d_in[4];

  char* ws = (char*)d_ws;
  const size_t MB = 1024 * 1024;
  u16t* xb  = (u16t*)(ws);               // [4096][1024] FRAG-TILED bf16 (8 MB); aliased by Yw
  u16t* Wqb = (u16t*)(ws + 8 * MB);      // W' [3072][1024] FRAG-TILED (Wq/Wk/Wv contiguous)
  u16t* Wob = (u16t*)(ws + 14 * MB);     // Wo LINEAR [1024][1024]
  u16t* Qw  = (u16t*)(ws + 16 * MB);     // [32][2048][64] bf16 head-split (pre-scaled)
  u16t* Ktw = (u16t*)(ws + 24 * MB);     // [32] fragment-tiled K'
  u16t* Vtw = (u16t*)(ws + 32 * MB);     // [32] fragment-tiled V'
  u16t* Yw  = xb;                        // safe alias: xb dead after QKV gemm

  convert_bf16<<<1920, 256, 0, stream>>>(x, Wq, Wk, Wv, Wo, xb, Wqb, Wob);
  // fused QKV, frag-streaming + panel register double-buffer
  gemm_fs<<<dim3(24, 32), 256, 0, stream>>>(xb, Wqb, Qw, Ktw, Vtw);
  flash_attn<<<dim3(32, 16), 256, 0, stream>>>(Qw, Ktw, Vtw, Yw);
  // out-proj: staged gemm, BM=64 -> 2 blocks/CU
  gemm_bt<0, 64><<<dim3(8, 64), 256, 0, stream>>>(
      Yw, Wob, d_out, d_out, d_out, 4096, 1024, 1024);
}

// Round 16
// 183.884 us; speedup vs baseline: 1.2109x; 1.0294x over previous
//
#include <hip/hip_runtime.h>
#include <hip/hip_bf16.h>

typedef __attribute__((ext_vector_type(8))) short bf16x8;   // 8 bf16 = 4 VGPRs
typedef __attribute__((ext_vector_type(8))) unsigned short u16x8;
typedef __attribute__((ext_vector_type(4))) float f32x4;
typedef unsigned short u16t;

#define DEVINL static __device__ __forceinline__

DEVINL u16t f2bf(float f) {
  union { __hip_bfloat16 h; u16t u; } cv;
  cv.h = __float2bfloat16(f);
  return cv.u;
}

// packed f32x2 -> bf16x2 (dst.lo = cvt(a), dst.hi = cvt(b)); no builtin on gfx950
DEVINL unsigned cvt_pk_bf16(float a, float b) {
  unsigned r;
  asm("v_cvt_pk_bf16_f32 %0, %1, %2" : "=v"(r) : "v"(a), "v"(b));
  return r;
}

// ---------------------------------------------------------------------------
// fp32 -> bf16 conversion + retiling. ALL operands frag-tiled now:
//   addr(m,k) = ((m>>4)*128 + (k>>3))*128 + (m&15)*8 + (k&7)
// Blocks: [0,512) x -> xb; [512,896) Wq/Wk/Wv -> W' [3072][1024];
//         [896,1024) Wo -> Wo' [1024][1024].
// ---------------------------------------------------------------------------
__global__ __launch_bounds__(256) void convert_bf16(
    const float* __restrict__ x,  const float* __restrict__ wq,
    const float* __restrict__ wk, const float* __restrict__ wv,
    const float* __restrict__ wo,
    u16t* __restrict__ xb, u16t* __restrict__ wqb, u16t* __restrict__ wob) {
  const int blk = blockIdx.x;
  const int tid = threadIdx.x;
  const int lane = tid & 63, w = tid >> 6;
  const int r = lane & 15, cw = lane >> 4;
  int mg, half, row0;
  const float* src; u16t* dst;
  if (blk < 512) {
    mg = blk >> 1; half = blk & 1; src = x; dst = xb; row0 = mg * 16;
  } else if (blk < 896) {
    const int wblk = blk - 512;
    mg = wblk >> 1; half = wblk & 1; dst = wqb;
    const int n0 = mg * 16;
    if (n0 < 1024)      { src = wq; row0 = n0; }
    else if (n0 < 2048) { src = wk; row0 = n0 - 1024; }
    else                { src = wv; row0 = n0 - 2048; }
  } else {
    const int oblk = blk - 896;
    mg = oblk >> 1; half = oblk & 1; src = wo; dst = wob; row0 = mg * 16;
  }
  #pragma unroll
  for (int ic = 0; ic < 4; ++ic) {
    const int c2 = half * 64 + w * 16 + ic * 4 + cw;   // chunk = k>>3
    const float4 v0 = *(const float4*)&src[(size_t)(row0 + r) * 1024 + c2 * 8];
    const float4 v1 = *(const float4*)&src[(size_t)(row0 + r) * 1024 + c2 * 8 + 4];
    u16x8 o;
    o[0] = f2bf(v0.x); o[1] = f2bf(v0.y); o[2] = f2bf(v0.z); o[3] = f2bf(v0.w);
    o[4] = f2bf(v1.x); o[5] = f2bf(v1.y); o[6] = f2bf(v1.z); o[7] = f2bf(v1.w);
    *(u16x8*)&dst[((size_t)mg * 128 + c2) * 128 + r * 8] = o;   // wave: 1KB contig
  }
}

// ---------------------------------------------------------------------------
// Frag-streaming GEMM (zero LDS, zero barriers) + panel register dbuf (R15).
// C[m,n] = sum_k A'[m,k]*B'[n,k], A'/B' FRAG-TILED. Wave tile (MI*16) x 64;
// block tile (MI*32) x 128. Per BK=32 panel: (MI+4) b128 frag loads + MI*4
// MFMAs; panel kp+1's loads issue BEFORE panel kp's MFMAs (fenced) -> MFMAs
// wait on counted vmcnt while the next panel flies.
// MODE 1 (QKV, MI=4): nz = n0>>10 selects Q (head-split, pre-scaled) /
//   K' / V' fragment-tiled scatter epilogues.
// MODE 0 (out-proj, MI=2): C0 = fp32 linear [M][1024].
// n-strip on grid.x (24 or 8, both %8==0): XCD-pinned B slices, L2-resident.
// ---------------------------------------------------------------------------
template <int MODE, int MI>
__global__ __launch_bounds__(256, 3) void gemm_fs(
    const u16t* __restrict__ A, const u16t* __restrict__ B,
    void* __restrict__ C0, void* __restrict__ C1, void* __restrict__ C2) {
  const int tid = threadIdx.x;
  const int lane = tid & 63;
  const int w = tid >> 6;
  const int wm = w >> 1, wn = w & 1;
  const int quad = lane >> 4, cl = lane & 15;
  const int m0 = blockIdx.y * (MI * 32);
  const int n0 = blockIdx.x * 128;

  // frag base: row-group ((m0>>4)+wm*MI+i), chunk kp*4+quad, elem cl*8
  const u16t* Ap = A + ((size_t)((m0 >> 4) + wm * MI) * 128 + quad) * 128 + cl * 8;
  const u16t* Bp = B + ((size_t)((n0 >> 4) + wn * 4) * 128 + quad) * 128 + cl * 8;

  f32x4 acc[MI][4] = {};
  bf16x8 afA[MI], bfA[4], afB[MI], bfB[4];

  #define LOADP(af_, bf_, kp_)                                                \
    {                                                                         \
      _Pragma("unroll")                                                       \
      for (int i = 0; i < MI; ++i)                                            \
        af_[i] = *(const bf16x8*)&Ap[(size_t)i * 16384 + (kp_) * 512];        \
      _Pragma("unroll")                                                       \
      for (int j = 0; j < 4; ++j)                                             \
        bf_[j] = *(const bf16x8*)&Bp[(size_t)j * 16384 + (kp_) * 512];        \
    }

  #define MFMAP(af_, bf_)                                                     \
    {                                                                         \
      _Pragma("unroll")                                                       \
      for (int i = 0; i < MI; ++i)                                            \
        _Pragma("unroll")                                                     \
        for (int j = 0; j < 4; ++j)                                           \
          acc[i][j] = __builtin_amdgcn_mfma_f32_16x16x32_bf16(af_[i], bf_[j], acc[i][j], 0, 0, 0); \
    }

  LOADP(afA, bfA, 0);
  __builtin_amdgcn_sched_barrier(0);
  #pragma unroll 1
  for (int kp = 0; kp < 32; kp += 2) {
    LOADP(afB, bfB, kp + 1);          // prefetch odd panel
    __builtin_amdgcn_sched_barrier(0);
    MFMAP(afA, bfA);                  // counted wait: afB/bfB stay in flight
    if (kp + 2 < 32) LOADP(afA, bfA, kp + 2);
    __builtin_amdgcn_sched_barrier(0);
    MFMAP(afB, bfB);
  }
  #undef LOADP
  #undef MFMAP

  const int nz = n0 >> 10;           // MODE1: weight id (block-uniform)
  #pragma unroll
  for (int i = 0; i < MI; ++i)
    #pragma unroll
    for (int j = 0; j < 4; ++j) {
      const int mb = m0 + wm * (MI * 16) + i * 16 + quad * 4;  // 4 consecutive m
      const int n  = n0 + wn * 64 + j * 16 + cl;
      if (MODE == 0) {
        #pragma unroll
        for (int r = 0; r < 4; ++r)
          ((float*)C0)[(size_t)(mb + r) * 1024 + n] = acc[i][j][r];
      } else {
        const int nw = n & 1023, h = nw >> 6, d = nw & 63;
        const int b = mb >> 11, tb = mb & 2047;
        const size_t bh = (size_t)(b * 16 + h);
        if (nz == 2) {
          ushort4 v4;
          v4.x = f2bf(acc[i][j][0]); v4.y = f2bf(acc[i][j][1]);
          v4.z = f2bf(acc[i][j][2]); v4.w = f2bf(acc[i][j][3]);
          const size_t addr = (bh << 17) +
              (size_t)(((d >> 4) * 256 + (tb >> 3)) * 128 + (d & 15) * 8 + (tb & 7));
          *(ushort4*)&((u16t*)C2)[addr] = v4;
        } else if (nz == 1) {
          const size_t basea = (bh << 17) +
              (size_t)(((tb >> 4) * 8 + (d >> 3)) * 128 + (d & 7));
          #pragma unroll
          for (int r = 0; r < 4; ++r)
            ((u16t*)C1)[basea + ((tb & 15) + r) * 8] = f2bf(acc[i][j][r]);
        } else {
          // Q: pre-scale by 0.125/ln2 so flash softmax is p = exp2(s)
          #pragma unroll
          for (int r = 0; r < 4; ++r)
            ((u16t*)C0)[(bh * 2048 + tb + r) * 64 + d] =
                f2bf(acc[i][j][r] * 0.18033688011112043f);
        }
      }
    }
}

// ---------------------------------------------------------------------------
// Flash attention (R13 structure, measured 61.5-62.7us, VGPR 100, no spill).
// ONE change vs R15: Y is written FRAG-TILED (m = b*2048+t, k = hd*64+d):
//   addr = ((m>>4)*128 + (k>>3))*128 + (m&15)*8 + (k&7)
// so the out-proj consumes it via the same verified gemm_fs frag loads.
// Same store count/width as the linear write -> predicted time-neutral.
// ---------------------------------------------------------------------------
__global__ __launch_bounds__(256, 2) void flash_attn(
    const u16t* __restrict__ Q, const u16t* __restrict__ Kt,
    const u16t* __restrict__ Vt, u16t* __restrict__ Y) {
  __shared__ u16t Ps[4 * 32 * 136];   // per-wave 32-row P scratch (34.8 KB)
  const int tid = threadIdx.x;
  const int lane = tid & 63;
  const int w = tid >> 6;
  const int quad = lane >> 4, cl = lane & 15;
  const int bh = blockIdx.x;          // bh on x: id%8==bh%8 pins bh to one XCD
  const int q0 = blockIdx.y * 128 + w * 32;
  const u16t* Kb = Kt + ((size_t)bh << 17);
  const u16t* Vb = Vt + ((size_t)bh << 17);

  bf16x8 aq[2][2];
  #pragma unroll
  for (int h = 0; h < 2; ++h)
    #pragma unroll
    for (int ks = 0; ks < 2; ++ks)
      aq[h][ks] = *(const bf16x8*)&Q[((size_t)bh * 2048 + q0 + 16 * h + cl) * 64 + ks * 32 + quad * 8];

  bf16x8 ones8;
  #pragma unroll
  for (int i = 0; i < 8; ++i) ones8[i] = (short)0x3F80;

  f32x4 o[2][4] = {};
  f32x4 psum[2] = {};

  u16t* Pw = &Ps[w * 32 * 136];

  for (int jt = 0; jt < 16; ++jt) {
    const int j0 = jt * 128;

    bf16x8 kf[2][8];
    #pragma unroll
    for (int ks = 0; ks < 2; ++ks)
      #pragma unroll
      for (int js = 0; js < 8; ++js)
        kf[ks][js] = *(const bf16x8*)&Kb[(size_t)((((j0 >> 4) + js) * 8 + ks * 4) * 128) + lane * 8];
    __builtin_amdgcn_sched_barrier(0);

    f32x4 s0[8] = {}, s1[8] = {};
    __builtin_amdgcn_s_setprio(1);
    #pragma unroll
    for (int ks = 0; ks < 2; ++ks) {
      #pragma unroll
      for (int js = 0; js < 8; ++js)
        s0[js] = __builtin_amdgcn_mfma_f32_16x16x32_bf16(kf[ks][js], aq[0][ks], s0[js], 0, 0, 0);
      #pragma unroll
      for (int js = 0; js < 8; ++js)
        s1[js] = __builtin_amdgcn_mfma_f32_16x16x32_bf16(kf[ks][js], aq[1][ks], s1[js], 0, 0, 0);
    }
    __builtin_amdgcn_s_setprio(0);

    bf16x8 vf[4][4];
    #pragma unroll
    for (int ks = 0; ks < 4; ++ks)
      #pragma unroll
      for (int ds = 0; ds < 4; ++ds)
        vf[ks][ds] = *(const bf16x8*)&Vb[(size_t)((ds * 256 + (j0 >> 3) + ks * 4) * 128) + lane * 8];
    __builtin_amdgcn_sched_barrier(0);

    #pragma unroll
    for (int js = 0; js < 8; ++js) {
      uint2 pk0, pk1;
      pk0.x = cvt_pk_bf16(__builtin_exp2f(s0[js][0]), __builtin_exp2f(s0[js][1]));
      pk0.y = cvt_pk_bf16(__builtin_exp2f(s0[js][2]), __builtin_exp2f(s0[js][3]));
      *(uint2*)&Pw[cl * 136 + js * 16 + quad * 4] = pk0;
      pk1.x = cvt_pk_bf16(__builtin_exp2f(s1[js][0]), __builtin_exp2f(s1[js][1]));
      pk1.y = cvt_pk_bf16(__builtin_exp2f(s1[js][2]), __builtin_exp2f(s1[js][3]));
      *(uint2*)&Pw[(16 + cl) * 136 + js * 16 + quad * 4] = pk1;
    }
    // same-wave LDS write->read ordered by lgkmcnt (no barrier)

    __builtin_amdgcn_s_setprio(1);
    #pragma unroll
    for (int ks = 0; ks < 4; ++ks) {
      const bf16x8 ap0 = *(const bf16x8*)&Pw[cl * 136 + ks * 32 + quad * 8];
      const bf16x8 ap1 = *(const bf16x8*)&Pw[(16 + cl) * 136 + ks * 32 + quad * 8];
      psum[0] = __builtin_amdgcn_mfma_f32_16x16x32_bf16(ap0, ones8, psum[0], 0, 0, 0);
      psum[1] = __builtin_amdgcn_mfma_f32_16x16x32_bf16(ap1, ones8, psum[1], 0, 0, 0);
      #pragma unroll
      for (int ds = 0; ds < 4; ++ds) {
        o[0][ds] = __builtin_amdgcn_mfma_f32_16x16x32_bf16(ap0, vf[ks][ds], o[0][ds], 0, 0, 0);
        o[1][ds] = __builtin_amdgcn_mfma_f32_16x16x32_bf16(ap1, vf[ks][ds], o[1][ds], 0, 0, 0);
      }
    }
    __builtin_amdgcn_s_setprio(0);
  }

  // Y frag-tiled write: m = b*2048 + q0 + 16h + quad*4 + r (q0 mult of 32),
  // k = hd*64 + ds*16 + cl. mg = (b*2048+q0)>>4 + h; k>>3 = hd*8+ds*2+(cl>>3).
  const int b = bh >> 4, hd = bh & 15;
  const int mgbase = (b * 2048 + q0) >> 4;
  #pragma unroll
  for (int h = 0; h < 2; ++h) {
    float inv[4];
    #pragma unroll
    for (int r = 0; r < 4; ++r) inv[r] = __builtin_amdgcn_rcpf(psum[h][r]);
    const size_t rowb = (size_t)((mgbase + h) * 128 + hd * 8) * 128;
    #pragma unroll
    for (int ds = 0; ds < 4; ++ds)
      #pragma unroll
      for (int r = 0; r < 4; ++r) {
        const size_t addr = rowb + (size_t)(ds * 2 + (cl >> 3)) * 128 +
                            (quad * 4 + r) * 8 + (cl & 7);
        Y[addr] = f2bf(o[h][ds][r] * inv[r]);
      }
  }
}

extern "C" void kernel_launch(void* const* d_in, const int* in_sizes, int n_in,
                              void* d_out, int out_size, void* d_ws, size_t ws_size,
                              hipStream_t stream) {
  (void)in_sizes; (void)n_in; (void)out_size; (void)ws_size;
  const float* x  = (const float*)d_in[0];
  const float* Wq = (const float*)d_in[1];
  const float* Wk = (const float*)d_in[2];
  const float* Wv = (const float*)d_in[3];
  const float* Wo = (const float*)d_in[4];

  char* ws = (char*)d_ws;
  const size_t MB = 1024 * 1024;
  u16t* xb  = (u16t*)(ws);               // x' [4096][1024] FRAG-TILED (8 MB); aliased by Yw
  u16t* Wqb = (u16t*)(ws + 8 * MB);      // W' [3072][1024] FRAG-TILED (Wq/Wk/Wv contiguous)
  u16t* Wob = (u16t*)(ws + 14 * MB);     // Wo' [1024][1024] FRAG-TILED
  u16t* Qw  = (u16t*)(ws + 16 * MB);     // [32][2048][64] bf16 head-split (pre-scaled)
  u16t* Ktw = (u16t*)(ws + 24 * MB);     // [32] fragment-tiled K'
  u16t* Vtw = (u16t*)(ws + 32 * MB);     // [32] fragment-tiled V'
  u16t* Yw  = xb;                        // safe alias: xb dead after QKV gemm

  convert_bf16<<<1024, 256, 0, stream>>>(x, Wq, Wk, Wv, Wo, xb, Wqb, Wob);
  // fused QKV: frag-streaming + panel dbuf
  gemm_fs<1, 4><<<dim3(24, 32), 256, 0, stream>>>(xb, Wqb, Qw, Ktw, Vtw);
  flash_attn<<<dim3(32, 16), 256, 0, stream>>>(Qw, Ktw, Vtw, Yw);
  // out-proj: frag-streaming too (Y' from flash, Wo' from convert)
  gemm_fs<0, 2><<<dim3(8, 64), 256, 0, stream>>>(
      Yw, Wob, d_out, d_out, d_out);
}